// Round 9
// baseline (45.171 us; speedup 1.0000x reference)
//
#include <hip/hip_runtime.h>

#define MAXLEN 768
#define DMODEL 512
// conv output length T = MAXLEN - KSIZE + 1 = 766

typedef float f32x4 __attribute__((ext_vector_type(4)));

// Kernel 1: read stream. One wave per row: predicated CACHED prefix reads
// (touched ~100 MiB of x stays L3-resident across graph replays), masked sum
// + edges -> (m0,m1,m2) into 1 MB scratch.
__global__ __launch_bounds__(256) void rowsum_kernel(
    const float* __restrict__ x,
    const int*   __restrict__ lengths,
    f32x4*       __restrict__ sums,   // [N] {m0,m1,m2,0}
    int n_rows)
{
    const int lane = threadIdx.x & 63;
    const int row  = (int)((blockIdx.x * blockDim.x + threadIdx.x) >> 6);
    if (row >= n_rows) return;

    const int L = lengths[row];
    const float* xr = x + (size_t)row * MAXLEN + 4 * lane;

    f32x4 va = {0.f, 0.f, 0.f, 0.f};
    f32x4 vb = {0.f, 0.f, 0.f, 0.f};
    f32x4 vc = {0.f, 0.f, 0.f, 0.f};
    if (4 * lane < L)
        va = *reinterpret_cast<const f32x4*>(xr);
    if (4 * lane + 256 < L)
        vb = *reinterpret_cast<const f32x4*>(xr + 256);
    if (4 * lane + 512 < L)
        vc = *reinterpret_cast<const f32x4*>(xr + 512);

    float e0 = 0.0f, e1 = 0.0f, e766 = 0.0f, e767 = 0.0f;
    float sa, sb, sc;
    {
        const int p = 4 * lane;
        const float v0 = (p + 0 < L) ? va.x : 0.0f;
        const float v1 = (p + 1 < L) ? va.y : 0.0f;
        const float v2 = (p + 2 < L) ? va.z : 0.0f;
        const float v3 = (p + 3 < L) ? va.w : 0.0f;
        sa = (v0 + v1) + (v2 + v3);
        e0 = v0; e1 = v1;                       // valid on lane 0 (L >= 3 always)
    }
    {
        const int p = 4 * lane + 256;
        const float v0 = (p + 0 < L) ? vb.x : 0.0f;
        const float v1 = (p + 1 < L) ? vb.y : 0.0f;
        const float v2 = (p + 2 < L) ? vb.z : 0.0f;
        const float v3 = (p + 3 < L) ? vb.w : 0.0f;
        sb = (v0 + v1) + (v2 + v3);
    }
    {
        const int p = 4 * lane + 512;
        const float v0 = (p + 0 < L) ? vc.x : 0.0f;
        const float v1 = (p + 1 < L) ? vc.y : 0.0f;
        const float v2 = (p + 2 < L) ? vc.z : 0.0f;
        const float v3 = (p + 3 < L) ? vc.w : 0.0f;
        sc = (v0 + v1) + (v2 + v3);
        e766 = v2; e767 = v3;                   // valid on lane 63 (0 if L<=766)
    }
    float s = (sa + sb) + sc;

#pragma unroll
    for (int off = 32; off > 0; off >>= 1)
        s += __shfl_xor(s, off, 64);
    e766 = __shfl(e766, 63, 64);
    e767 = __shfl(e767, 63, 64);

    if (lane == 0) {
        const float inv = 1.0f / 766.0f;
        f32x4 m;
        m.x = (s - e766 - e767) * inv;
        m.y = (s - e0 - e767) * inv;
        m.z = (s - e0 - e1) * inv;
        m.w = 0.0f;
        sums[row] = m;
    }
}

// Kernel 2: pure write stream. One wave per row: out[row,:] = b + m @ w^T.
// Dense back-to-back nt stores -> HBM write rate ~7 TB/s (fill-kernel proven).
__global__ __launch_bounds__(256) void expand_kernel(
    const f32x4* __restrict__ sums,
    const float* __restrict__ w,   // [DMODEL][3] row-major
    const float* __restrict__ b,   // [DMODEL]
    float*       __restrict__ out, // [N][DMODEL]
    int n_rows)
{
    const int lane = threadIdx.x & 63;
    const int row  = (int)((blockIdx.x * blockDim.x + threadIdx.x) >> 6);
    if (row >= n_rows) return;

    const f32x4 m = sums[row];                  // L2-hot
    const float m0 = m.x, m1 = m.y, m2 = m.z;

    float* orow = out + (size_t)row * DMODEL;
#pragma unroll
    for (int j = 0; j < 2; ++j) {
        const int d = 4 * lane + 256 * j;
        const f32x4 wa = *reinterpret_cast<const f32x4*>(w + 3 * d + 0);
        const f32x4 wb = *reinterpret_cast<const f32x4*>(w + 3 * d + 4);
        const f32x4 wc = *reinterpret_cast<const f32x4*>(w + 3 * d + 8);
        const f32x4 bb = *reinterpret_cast<const f32x4*>(b + d);
        f32x4 o;
        o.x = bb.x + m0 * wa.x + m1 * wa.y + m2 * wa.z;
        o.y = bb.y + m0 * wa.w + m1 * wb.x + m2 * wb.y;
        o.z = bb.z + m0 * wb.z + m1 * wb.w + m2 * wc.x;
        o.w = bb.w + m0 * wc.y + m1 * wc.z + m2 * wc.w;
        __builtin_nontemporal_store(o, reinterpret_cast<f32x4*>(orow + d));
    }
}

extern "C" void kernel_launch(void* const* d_in, const int* in_sizes, int n_in,
                              void* d_out, int out_size, void* d_ws, size_t ws_size,
                              hipStream_t stream) {
    const float* x       = (const float*)d_in[0];
    const int*   lengths = (const int*)  d_in[1];
    const float* conv_w  = (const float*)d_in[2];
    const float* conv_b  = (const float*)d_in[3];
    float* out = (float*)d_out;
    f32x4* sums = (f32x4*)d_ws;                   // 65536 * 16 B = 1 MB scratch

    const int n_rows = in_sizes[1];               // 65536
    const int grid = (n_rows + 3) / 4;            // 4 waves/block, 1 row/wave

    rowsum_kernel<<<grid, 256, 0, stream>>>(x, lengths, sums, n_rows);
    expand_kernel<<<grid, 256, 0, stream>>>(sums, conv_w, conv_b, out, n_rows);
}